// Round 1
// 176.736 us; speedup vs baseline: 1.0392x; 1.0392x over previous
//
#include <hip/hip_runtime.h>
#include <hip/hip_fp16.h>

#define N_NODES 50000
#define N_EDGES 800000
#define FDIM 64
#define N_GRAPHS 500
#define OUTF 10
#define SENT N_NODES
#define ROWCAP 64                       // fixed CSR row capacity; Poisson(16), P(deg>64)~1e-18
#define FILLB 4096
#define SEGB ((N_NODES + 256) / 256)    // 196

struct __align__(8) H4 { __half2 a, b; };

__device__ __forceinline__ float rl(float v, int l) {
    return __int_as_float(__builtin_amdgcn_readlane(__float_as_int(v), l));
}

// ---------------- single-pass CSR build (deg doubles as cursor) + seg starts ----------------
// XCD affinity: owner(node)=(n>>5)&7, block proxy = blockIdx&7 (heuristic only;
// every edge is handled by exactly one block regardless of placement).
__global__ __launch_bounds__(256) void fill_seg(
    const int* __restrict__ src, const int* __restrict__ dst,
    int* __restrict__ deg, int* __restrict__ csr,
    const int* __restrict__ batch, int* __restrict__ start) {
    int bid = blockIdx.x;
    if (bid < FILLB) {
        int myx = bid & 7, cid = bid >> 3, nch = FILLB >> 3;
        for (int e = cid * 256 + threadIdx.x; e < N_EDGES; e += nch * 256) {
            int d = dst[e];
            if (((d >> 5) & 7) != myx) continue;
            int pos = atomicAdd(&deg[d], 1);
            if (pos < ROWCAP) csr[d * ROWCAP + pos] = src[e];
        }
    } else {
        int i = (bid - FILLB) * 256 + threadIdx.x;
        if (i > N_NODES) return;
        int b  = (i < N_NODES) ? batch[i] : N_GRAPHS;
        int bp = (i == 0) ? -1 : batch[i - 1];
        for (int g = bp + 1; g <= b; ++g) start[g] = i;
    }
}

// ---------------- dinv + prescale x -> fp16, + zero sentinel rows ----------------
// grid = N_NODES*16/256 = 3125 blocks (was 196: <1 block/CU, latency-bound).
// One float4 per thread, full occupancy, pure streaming.
__global__ __launch_bounds__(256) void prescale(
    const int* __restrict__ deg, const float* __restrict__ x,
    float* __restrict__ dinv, __half* __restrict__ hsx, __half* __restrict__ hs1) {
    if (blockIdx.x == 0 && threadIdx.x < 2 * FDIM) {
        __half z = __float2half(0.f);
        if (threadIdx.x < FDIM) hsx[(size_t)N_NODES * FDIM + threadIdx.x] = z;
        else                    hs1[(size_t)N_NODES * FDIM + threadIdx.x - FDIM] = z;
    }
    int gid = blockIdx.x * 256 + threadIdx.x;   // float4 index; grid*256 == N_NODES*16 exact
    int n = gid >> 4;
    float dn = rsqrtf((float)deg[n] + 1.0f);    // +1 self-loop
    if ((gid & 15) == 0) dinv[n] = dn;
    float4 vv = ((const float4*)x)[gid];
    H4 o;
    o.a = __floats2half2_rn(vv.x * dn, vv.y * dn);
    o.b = __floats2half2_rn(vv.z * dn, vv.w * dn);
    ((H4*)hsx)[gid] = o;
}

// ---------------- fused GCN layer: 4 nodes/wave, 16 lanes/node ----------------
// csr indices double-buffered: next batch's 2x int4 issued BEFORE this batch's
// feature loads. Prefetch clamps to min(base+8,56) -> always inside the node's
// fixed 64-int row; pad garbage masked to SENT before the feature load.
// POOL: keep layer-2 output in registers and atomically accumulate the graph
// mean-pool sums directly (batch is sorted: the wave's 4 consecutive nodes are
// same-graph ~97% of the time -> 1 atomic/lane/wave fast path). Removes the
// 6.4MB hsx write AND pool_head's 6.4MB latency-bound re-read.
template <bool SCALE_OUT, bool POOL>
__global__ __launch_bounds__(256) void gcn_fused(
    const int* __restrict__ deg, const int* __restrict__ csr,
    const float* __restrict__ dinv, const __half* __restrict__ hs,
    const float* __restrict__ W, const float* __restrict__ bias,
    __half* __restrict__ out, const int* __restrict__ batch,
    float* __restrict__ pooled) {
    __shared__ float Ws[FDIM * FDIM];
    int tid = threadIdx.x;
    int lane = tid & 63;
    int L = lane & 15, q = lane >> 4;
    int nodeBase = (blockIdx.x * 4 + (tid >> 6)) * 4;   // grid = 3125 exact
    int myN = nodeBase + q;

    float dn = dinv[myN];
    int d = min(deg[myN], ROWCAP);
    int row = myN << 6;                      // myN * ROWCAP
    int dpad = (d + 7) & ~7;

    H4 sv = *(const H4*)(hs + (size_t)myN * FDIM + 4 * L);  // self term
    __half2 z2 = __floats2half2_rn(0.f, 0.f);
    __half2 c0a = sv.a, c0b = sv.b;          // chain 0 seeded with self term
    __half2 c1a = z2,   c1b = z2;            // chain 1

    #pragma unroll
    for (int i = 0; i < 16; ++i) Ws[tid + i * 256] = W[tid + i * 256];
    __syncthreads();

    int4 sA = *(const int4*)(csr + row);     // prime the index pipeline
    int4 sB = *(const int4*)(csr + row + 4);
    for (int base = 0; base < dpad; base += 8) {
        int nxt = min(base + 8, 56);         // stays inside this node's row
        int4 nA = *(const int4*)(csr + row + nxt);
        int4 nB = *(const int4*)(csr + row + nxt + 4);
        int ss[8] = { sA.x, sA.y, sA.z, sA.w, sB.x, sB.y, sB.z, sB.w };
        #pragma unroll
        for (int j = 0; j < 8; ++j) {
            int e = base + j;
            int s = (e < d) ? ss[j] : SENT;  // mask pad garbage BEFORE the load
            H4 hv = *(const H4*)(hs + (size_t)s * FDIM + 4 * L);
            if (j & 1) { c1a = __hadd2(c1a, hv.a); c1b = __hadd2(c1b, hv.b); }
            else       { c0a = __hadd2(c0a, hv.a); c0b = __hadd2(c0b, hv.b); }
        }
        sA = nA; sB = nB;
    }
    // combine chains in fp32, scale by dinv
    float2 t0a = __half22float2(c0a), t1a = __half22float2(c1a);
    float2 t0b = __half22float2(c0b), t1b = __half22float2(c1b);
    float4 acc = make_float4((t0a.x + t1a.x) * dn, (t0a.y + t1a.y) * dn,
                             (t0b.x + t1b.x) * dn, (t0b.y + t1b.y) * dn);

    float b0 = bias[lane];
    float o0 = b0, o1 = b0, o2 = b0, o3 = b0;
    #pragma unroll
    for (int k = 0; k < 64; ++k) {
        float wv = Ws[k * 64 + lane];
        int sl = k >> 2;
        float comp = (k & 3) == 0 ? acc.x : (k & 3) == 1 ? acc.y : (k & 3) == 2 ? acc.z : acc.w;
        o0 = fmaf(rl(comp, sl),      wv, o0);
        o1 = fmaf(rl(comp, sl + 16), wv, o1);
        o2 = fmaf(rl(comp, sl + 32), wv, o2);
        o3 = fmaf(rl(comp, sl + 48), wv, o3);
    }
    o0 = fmaxf(o0, 0.f); o1 = fmaxf(o1, 0.f); o2 = fmaxf(o2, 0.f); o3 = fmaxf(o3, 0.f);
    if (POOL) {
        // lane holds feature `lane` of nodes nodeBase+0..3; batch sorted
        int g0 = batch[nodeBase], g3 = batch[nodeBase + 3];
        if (g0 == g3) {
            atomicAdd(&pooled[g0 * FDIM + lane], o0 + o1 + o2 + o3);
        } else {
            int g1 = batch[nodeBase + 1], g2 = batch[nodeBase + 2];
            atomicAdd(&pooled[g0 * FDIM + lane], o0);
            atomicAdd(&pooled[g1 * FDIM + lane], o1);
            atomicAdd(&pooled[g2 * FDIM + lane], o2);
            atomicAdd(&pooled[g3 * FDIM + lane], o3);
        }
        return;
    }
    if (SCALE_OUT) {   // pre-scale rows by dinv for the next layer's gather
        o0 *= rl(dn, 0); o1 *= rl(dn, 16); o2 *= rl(dn, 32); o3 *= rl(dn, 48);
    }
    out[(size_t)(nodeBase + 0) * FDIM + lane] = __float2half_rn(o0);
    out[(size_t)(nodeBase + 1) * FDIM + lane] = __float2half_rn(o1);
    out[(size_t)(nodeBase + 2) * FDIM + lane] = __float2half_rn(o2);
    out[(size_t)(nodeBase + 3) * FDIM + lane] = __float2half_rn(o3);
}

// ---------------- tiny head: mean + linear + log_softmax from pooled sums ----------------
// 125 blocks x 4 waves = 500 graphs, one wave per graph, register-only.
__global__ __launch_bounds__(256) void head(
    const float* __restrict__ pooled, const int* __restrict__ start,
    const float* __restrict__ Wc, const float* __restrict__ bc,
    float* __restrict__ out) {
    int tid = threadIdx.x;
    int lane = tid & 63;
    int g = blockIdx.x * 4 + (tid >> 6);
    int cnt = start[g + 1] - start[g];
    float c = (float)(cnt > 1 ? cnt : 1);
    float pm = pooled[g * FDIM + lane] / c;

    int j = (lane < OUTF) ? lane : 0;        // clamp keeps Wc/bc reads in-bounds
    float a = bc[j];
    #pragma unroll
    for (int k = 0; k < 64; ++k) a = fmaf(rl(pm, k), Wc[k * OUTF + j], a);

    float m = -1e30f;
    #pragma unroll
    for (int i = 0; i < OUTF; ++i) m = fmaxf(m, rl(a, i));
    float s = 0.f;
    #pragma unroll
    for (int i = 0; i < OUTF; ++i) s += __expf(rl(a, i) - m);
    float lse = m + __logf(s);
    if (lane < OUTF) out[g * OUTF + lane] = a - lse;
}

extern "C" void kernel_launch(void* const* d_in, const int* in_sizes, int n_in,
                              void* d_out, int out_size, void* d_ws, size_t ws_size,
                              hipStream_t stream) {
    const float* x     = (const float*)d_in[0];
    const int*   ei    = (const int*)d_in[1];
    const int*   batch = (const int*)d_in[2];
    const float* W1    = (const float*)d_in[3];
    const float* b1    = (const float*)d_in[4];
    const float* W2    = (const float*)d_in[5];
    const float* b2    = (const float*)d_in[6];
    const float* Wc    = (const float*)d_in[7];
    const float* bc    = (const float*)d_in[8];
    float* out = (float*)d_out;

    const int* src = ei;
    const int* dst = ei + N_EDGES;

    // workspace layout (int units); deg+pooled contiguous -> one memset.
    // csr base offset = 50000+32000+50000+504 = 132504 ints (divisible by 4 -> 16B aligned)
    int*    ws     = (int*)d_ws;
    int*    deg    = ws;                                  // 50000 (memset to 0)
    float*  pooled = (float*)(deg + N_NODES);             // 500*64 = 32000 (memset to 0)
    float*  dinv   = pooled + N_GRAPHS * FDIM;            // 50000
    int*    start  = (int*)(dinv + N_NODES);              // 504
    int*    csr    = start + N_GRAPHS + 4;                // 50000*64 = 3.2M ints
    __half* hsx    = (__half*)(csr + N_NODES * ROWCAP);   // (N_NODES+1)*64 halves
    __half* hs1    = hsx + (size_t)(N_NODES + 1) * FDIM;

    hipMemsetAsync(deg, 0, (N_NODES + N_GRAPHS * FDIM) * sizeof(int), stream);

    fill_seg <<<FILLB + SEGB, 256, 0, stream>>>(src, dst, deg, csr, batch, start);
    prescale <<<(N_NODES * 16) / 256, 256, 0, stream>>>(deg, x, dinv, hsx, hs1);

    const int gcnGrid = N_NODES / 16;  // 3125 exact
    gcn_fused<true , false><<<gcnGrid, 256, 0, stream>>>(deg, csr, dinv, hsx, W1, b1, hs1, nullptr, nullptr);
    gcn_fused<false, true ><<<gcnGrid, 256, 0, stream>>>(deg, csr, dinv, hs1, W2, b2, nullptr, batch, pooled);

    head<<<N_GRAPHS / 4, 256, 0, stream>>>(pooled, start, Wc, bc, out);
}